// Round 2
// baseline (718.859 us; speedup 1.0000x reference)
//
#include <hip/hip_runtime.h>

#define NEG_SLOPE 0.2f

// ---------------------------------------------------------------------------
// Zero an int array (replaces hipMemsetAsync — keep launch path kernels-only
// to minimize graph-capture surface).
// ---------------------------------------------------------------------------
__global__ void zero_kernel(int* __restrict__ p, int n) {
    int i = blockIdx.x * blockDim.x + threadIdx.x;
    if (i < n) p[i] = 0;
}

// ---------------------------------------------------------------------------
// Edge-index normalization: harness may hand us int32 or int64 edge data.
// Detect on device (uniform decision) and emit int32 src/dst arrays.
// ---------------------------------------------------------------------------
__global__ void detect_convert_kernel(const void* __restrict__ ei_raw, int E,
                                      int* __restrict__ src32,
                                      int* __restrict__ dst32) {
    const int* as32 = (const int*)ei_raw;
    const long long* as64 = (const long long*)ei_raw;
    // If data is int64: first 16 values are small non-negative. If int32: the
    // 64-bit view packs two random ints -> huge values w.h.p.
    bool is64 = true;
    for (int i = 0; i < 16; ++i) {
        long long v = as64[i];
        if (!(v >= 0 && v < 2147483648LL)) { is64 = false; }
    }
    int i = blockIdx.x * blockDim.x + threadIdx.x;
    if (i < E) {
        if (is64) {
            src32[i] = (int)as64[i];
            dst32[i] = (int)as64[(size_t)E + i];
        } else {
            src32[i] = as32[i];
            dst32[i] = as32[(size_t)E + i];
        }
    }
}

__global__ void count_kernel(const int* __restrict__ dst, int E,
                             int* __restrict__ cnt) {
    int i = blockIdx.x * blockDim.x + threadIdx.x;
    if (i < E) atomicAdd(&cnt[dst[i]], 1);
}

// Single-block exclusive scan: thread-local serial chunks + Hillis-Steele over
// 1024 thread totals (avoids ~1000 syncthreads of a naive element scan).
__global__ __launch_bounds__(1024) void scan_kernel(const int* __restrict__ cnt,
                                                    int* __restrict__ off,
                                                    int* __restrict__ cursor,
                                                    int N) {
    __shared__ int s[1024];
    int t = threadIdx.x;
    int chunk = (N + 1023) >> 10;
    int beg = t * chunk;
    int end = min(beg + chunk, N);
    int sum = 0;
    for (int i = beg; i < end; ++i) sum += cnt[i];
    s[t] = sum;
    __syncthreads();
    for (int o = 1; o < 1024; o <<= 1) {
        int add = (t >= o) ? s[t - o] : 0;
        __syncthreads();
        s[t] += add;
        __syncthreads();
    }
    int run = s[t] - sum;  // exclusive prefix for this thread's chunk
    for (int i = beg; i < end; ++i) {
        off[i] = run;
        cursor[i] = run;
        run += cnt[i];
    }
    if (t == 1023) off[N] = s[1023];
}

__global__ void scatter_kernel(const int* __restrict__ src,
                               const int* __restrict__ dst, int E,
                               int* __restrict__ cursor,
                               int* __restrict__ csr_src) {
    int i = blockIdx.x * blockDim.x + threadIdx.x;
    if (i < E) {
        int p = atomicAdd(&cursor[dst[i]], 1);
        csr_src[p] = src[i];
    }
}

// ---------------------------------------------------------------------------
// GEMM: H = X[N,128] @ W[128,128], fp32 vector ALU.
// 128 threads/block = (tx 0..31) x (ty 0..3); each thread computes a 4x4 tile;
// block covers 16 rows x 128 cols. X tile staged in LDS (padded stride 132 ->
// broadcast reads, no conflicts); W rows read as float4 from global (64 KB,
// L2-resident across the 3125 blocks).
// ---------------------------------------------------------------------------
__global__ __launch_bounds__(128) void gemm128_kernel(
    const float* __restrict__ X, const float* __restrict__ W,
    float* __restrict__ Hout, int N) {
    __shared__ float sX[16 * 132];
    int t = threadIdx.x;
    int tx = t & 31;
    int ty = t >> 5;
    int row0 = blockIdx.x * 16;

    for (int i = t; i < 512; i += 128) {   // 16 rows * 32 float4
        int r = i >> 5;
        int kq = i & 31;
        int row = row0 + r;
        float4 v = make_float4(0.f, 0.f, 0.f, 0.f);
        if (row < N) v = ((const float4*)X)[(size_t)row * 32 + kq];
        *(float4*)&sX[r * 132 + kq * 4] = v;
    }
    __syncthreads();

    float acc[4][4] = {};
    const float4* W4 = (const float4*)W;
#pragma unroll 4
    for (int k = 0; k < 128; ++k) {
        float4 b = W4[k * 32 + tx];
#pragma unroll
        for (int i = 0; i < 4; ++i) {
            float a = sX[(ty * 4 + i) * 132 + k];
            acc[i][0] += a * b.x;
            acc[i][1] += a * b.y;
            acc[i][2] += a * b.z;
            acc[i][3] += a * b.w;
        }
    }
#pragma unroll
    for (int i = 0; i < 4; ++i) {
        int row = row0 + ty * 4 + i;
        if (row < N) {
            float4 o = make_float4(acc[i][0], acc[i][1], acc[i][2], acc[i][3]);
            ((float4*)Hout)[(size_t)row * 32 + tx] = o;
        }
    }
}

// ---------------------------------------------------------------------------
// alpha_s[n,h] = sum_c h[n,h,c]*a_src[h,c]; same for alpha_d. One block/node.
// a_src flattened [H*C] == h row layout, so products are elementwise.
// ---------------------------------------------------------------------------
template <int C>
__global__ __launch_bounds__(128) void alpha_kernel(
    const float* __restrict__ h, const float* __restrict__ asrc,
    const float* __restrict__ adst, float* __restrict__ alpha_s,
    float* __restrict__ alpha_d) {
    constexpr int H = 128 / C;
    int n = blockIdx.x;
    int t = threadIdx.x;
    float hv = h[(size_t)n * 128 + t];
    __shared__ float s1[128];
    __shared__ float s2[128];
    s1[t] = hv * asrc[t];
    s2[t] = hv * adst[t];
    __syncthreads();
#pragma unroll
    for (int o = C / 2; o > 0; o >>= 1) {
        if ((t & (C - 1)) < o) {
            s1[t] += s1[t + o];
            s2[t] += s2[t + o];
        }
        __syncthreads();
    }
    if ((t & (C - 1)) == 0) {
        int hh = t / C;
        alpha_s[(size_t)n * H + hh] = s1[t];
        alpha_d[(size_t)n * H + hh] = s2[t];
    }
}

// ---------------------------------------------------------------------------
// Per-dst-node segment softmax + weighted aggregation. One 128-thread block
// per node. Edge idx 0 is the implicit self-loop; idx>=1 come from CSR.
// Phase 1: per-head max (block reduce). Phase 2: per-head sum of exp.
// Phase 3: chunked accumulate; weights staged in LDS, h rows gathered
// coalesced (128 consecutive floats per edge).
// ---------------------------------------------------------------------------
template <int H, int C>
__global__ __launch_bounds__(128) void gather_kernel(
    const float* __restrict__ h, const float* __restrict__ as_,
    const float* __restrict__ ad_, const int* __restrict__ off,
    const int* __restrict__ csr_src, const float* __restrict__ bias,
    float* __restrict__ out) {
    int n = blockIdx.x;
    int t = threadIdx.x;
    int beg = off[n];
    int total = off[n + 1] - beg + 1;  // + self loop

    float adv[H];
#pragma unroll
    for (int hh = 0; hh < H; ++hh) adv[hh] = ad_[(size_t)n * H + hh];

    __shared__ float red[H * 128];

    // Phase 1: max per head
    float mloc[H];
#pragma unroll
    for (int hh = 0; hh < H; ++hh) mloc[hh] = -3.4e38f;
    for (int idx = t; idx < total; idx += 128) {
        int src = (idx == 0) ? n : csr_src[beg + idx - 1];
#pragma unroll
        for (int hh = 0; hh < H; ++hh) {
            float s = as_[(size_t)src * H + hh] + adv[hh];
            s = (s > 0.f) ? s : NEG_SLOPE * s;
            mloc[hh] = fmaxf(mloc[hh], s);
        }
    }
#pragma unroll
    for (int hh = 0; hh < H; ++hh) red[hh * 128 + t] = mloc[hh];
    __syncthreads();
    for (int o = 64; o > 0; o >>= 1) {
        if (t < o) {
#pragma unroll
            for (int hh = 0; hh < H; ++hh)
                red[hh * 128 + t] = fmaxf(red[hh * 128 + t], red[hh * 128 + t + o]);
        }
        __syncthreads();
    }
    float m[H];
#pragma unroll
    for (int hh = 0; hh < H; ++hh) m[hh] = red[hh * 128];
    __syncthreads();

    // Phase 2: sum of exp per head
    float sloc[H];
#pragma unroll
    for (int hh = 0; hh < H; ++hh) sloc[hh] = 0.f;
    for (int idx = t; idx < total; idx += 128) {
        int src = (idx == 0) ? n : csr_src[beg + idx - 1];
#pragma unroll
        for (int hh = 0; hh < H; ++hh) {
            float s = as_[(size_t)src * H + hh] + adv[hh];
            s = (s > 0.f) ? s : NEG_SLOPE * s;
            sloc[hh] += __expf(s - m[hh]);
        }
    }
#pragma unroll
    for (int hh = 0; hh < H; ++hh) red[hh * 128 + t] = sloc[hh];
    __syncthreads();
    for (int o = 64; o > 0; o >>= 1) {
        if (t < o) {
#pragma unroll
            for (int hh = 0; hh < H; ++hh)
                red[hh * 128 + t] += red[hh * 128 + t + o];
        }
        __syncthreads();
    }
    float inv[H];
#pragma unroll
    for (int hh = 0; hh < H; ++hh) inv[hh] = 1.f / red[hh * 128];
    __syncthreads();

    // Phase 3: weighted accumulation
    __shared__ int s_src[128];
    __shared__ float s_w[128 * H];
    const int hh_t = t / C;
    float acc = 0.f;
    for (int base = 0; base < total; base += 128) {
        int cnt2 = min(128, total - base);
        if (t < cnt2) {
            int idx = base + t;
            int src = (idx == 0) ? n : csr_src[beg + idx - 1];
            s_src[t] = src;
#pragma unroll
            for (int hh = 0; hh < H; ++hh) {
                float s = as_[(size_t)src * H + hh] + adv[hh];
                s = (s > 0.f) ? s : NEG_SLOPE * s;
                s_w[t * H + hh] = __expf(s - m[hh]) * inv[hh];
            }
        }
        __syncthreads();
        for (int j = 0; j < cnt2; ++j) {
            acc += s_w[j * H + hh_t] * h[(size_t)s_src[j] * 128 + t];
        }
        __syncthreads();
    }
    out[(size_t)n * 128 + t] = fmaxf(acc + bias[t], 0.f);
}

// ---------------------------------------------------------------------------
extern "C" void kernel_launch(void* const* d_in, const int* in_sizes, int n_in,
                              void* d_out, int out_size, void* d_ws,
                              size_t ws_size, hipStream_t stream) {
    const float* x   = (const float*)d_in[0];
    const void*  ei  = d_in[1];
    const float* W0  = (const float*)d_in[2];
    const float* as0 = (const float*)d_in[3];
    const float* ad0 = (const float*)d_in[4];
    const float* b0  = (const float*)d_in[5];
    const float* W1  = (const float*)d_in[6];
    const float* as1 = (const float*)d_in[7];
    const float* ad1 = (const float*)d_in[8];
    const float* b1  = (const float*)d_in[9];
    const float* W2  = (const float*)d_in[10];
    const float* as2 = (const float*)d_in[11];
    const float* ad2 = (const float*)d_in[12];
    const float* b2  = (const float*)d_in[13];

    int N = in_sizes[0] / 128;
    int E = in_sizes[1] / 2;
    float* out = (float*)d_out;

    // workspace layout (all 4-byte types; d_ws is 256B-aligned)
    float* h       = (float*)d_ws;                       // N*128
    float* alpha_s = h + (size_t)N * 128;                // N*4 (max H)
    float* alpha_d = alpha_s + (size_t)N * 4;            // N*4
    int*   cnt     = (int*)(alpha_d + (size_t)N * 4);    // N
    int*   off     = cnt + N;                            // N+1
    int*   cursor  = off + N + 1;                        // N
    int*   src32   = cursor + N;                         // E
    int*   dst32   = src32 + E;                          // E
    int*   csr     = dst32 + E;                          // E

    int eb = (E + 255) / 256;
    int nb = (N + 255) / 256;

    zero_kernel<<<nb, 256, 0, stream>>>(cnt, N);
    detect_convert_kernel<<<eb, 256, 0, stream>>>(ei, E, src32, dst32);
    count_kernel<<<eb, 256, 0, stream>>>(dst32, E, cnt);
    scan_kernel<<<1, 1024, 0, stream>>>(cnt, off, cursor, N);
    scatter_kernel<<<eb, 256, 0, stream>>>(src32, dst32, E, cursor, csr);

    int gb = (N + 15) / 16;

    // layer 0: H=4, C=32
    gemm128_kernel<<<gb, 128, 0, stream>>>(x, W0, h, N);
    alpha_kernel<32><<<N, 128, 0, stream>>>(h, as0, ad0, alpha_s, alpha_d);
    gather_kernel<4, 32><<<N, 128, 0, stream>>>(h, alpha_s, alpha_d, off, csr, b0, out);

    // layer 1: H=4, C=32
    gemm128_kernel<<<gb, 128, 0, stream>>>(out, W1, h, N);
    alpha_kernel<32><<<N, 128, 0, stream>>>(h, as1, ad1, alpha_s, alpha_d);
    gather_kernel<4, 32><<<N, 128, 0, stream>>>(h, alpha_s, alpha_d, off, csr, b1, out);

    // layer 2: H=1, C=128
    gemm128_kernel<<<gb, 128, 0, stream>>>(out, W2, h, N);
    alpha_kernel<128><<<N, 128, 0, stream>>>(h, as2, ad2, alpha_s, alpha_d);
    gather_kernel<1, 128><<<N, 128, 0, stream>>>(h, alpha_s, alpha_d, off, csr, b2, out);
}

// Round 3
// 514.859 us; speedup vs baseline: 1.3962x; 1.3962x over previous
//
#include <hip/hip_runtime.h>

#define NEG_SLOPE 0.2f

// ---------------------------------------------------------------------------
__global__ void zero_kernel(int* __restrict__ p, int n) {
    int i = blockIdx.x * blockDim.x + threadIdx.x;
    if (i < n) p[i] = 0;
}

// ---------------------------------------------------------------------------
// Edge-index normalization + dst counting fused (saves one 6.4MB pass).
// Harness may hand us int32 or int64 edge data; detect on device.
// ---------------------------------------------------------------------------
__global__ void detect_convert_count_kernel(const void* __restrict__ ei_raw,
                                            int E, int* __restrict__ src32,
                                            int* __restrict__ dst32,
                                            int* __restrict__ cnt) {
    const int* as32 = (const int*)ei_raw;
    const long long* as64 = (const long long*)ei_raw;
    bool is64 = true;
    for (int i = 0; i < 16; ++i) {
        long long v = as64[i];
        if (!(v >= 0 && v < 2147483648LL)) { is64 = false; }
    }
    int i = blockIdx.x * blockDim.x + threadIdx.x;
    if (i < E) {
        int s, d;
        if (is64) {
            s = (int)as64[i];
            d = (int)as64[(size_t)E + i];
        } else {
            s = as32[i];
            d = as32[(size_t)E + i];
        }
        src32[i] = s;
        dst32[i] = d;
        atomicAdd(&cnt[d], 1);
    }
}

// ---------------------------------------------------------------------------
// Hierarchical exclusive scan over cnt[N] -> off[N+1], cursor[N].
// scan1: 256 blocks compute partial sums of contiguous chunks.
// scan2: 1 block exclusive-scans the 256 partials (writes off[N]=total).
// scan3: 256 blocks scan their chunk locally and add the block base.
// ---------------------------------------------------------------------------
#define SCAN_NB 256

__global__ __launch_bounds__(256) void scan1_kernel(const int* __restrict__ cnt,
                                                    int* __restrict__ partial,
                                                    int N) {
    __shared__ int s[256];
    int b = blockIdx.x;
    int t = threadIdx.x;
    int csize = (N + SCAN_NB - 1) / SCAN_NB;
    int beg = b * csize;
    int end = min(beg + csize, N);
    int sum = 0;
    for (int i = beg + t; i < end; i += 256) sum += cnt[i];
    s[t] = sum;
    __syncthreads();
    for (int o = 128; o > 0; o >>= 1) {
        if (t < o) s[t] += s[t + o];
        __syncthreads();
    }
    if (t == 0) partial[b] = s[0];
}

__global__ __launch_bounds__(256) void scan2_kernel(int* __restrict__ partial,
                                                    int* __restrict__ off,
                                                    int N) {
    __shared__ int s[256];
    int t = threadIdx.x;
    int v = partial[t];
    s[t] = v;
    __syncthreads();
    for (int o = 1; o < 256; o <<= 1) {
        int add = (t >= o) ? s[t - o] : 0;
        __syncthreads();
        s[t] += add;
        __syncthreads();
    }
    partial[t] = s[t] - v;  // exclusive
    if (t == 255) off[N] = s[255];
}

__global__ __launch_bounds__(256) void scan3_kernel(const int* __restrict__ cnt,
                                                    const int* __restrict__ partial,
                                                    int* __restrict__ off,
                                                    int* __restrict__ cursor,
                                                    int N) {
    __shared__ int s[256];
    int b = blockIdx.x;
    int t = threadIdx.x;
    int csize = (N + SCAN_NB - 1) / SCAN_NB;
    int beg = b * csize;
    int end = min(beg + csize, N);
    int base = partial[b];
    for (int r = beg; r < end; r += 256) {
        int i = r + t;
        int v = (i < end) ? cnt[i] : 0;
        s[t] = v;
        __syncthreads();
        for (int o = 1; o < 256; o <<= 1) {
            int add = (t >= o) ? s[t - o] : 0;
            __syncthreads();
            s[t] += add;
            __syncthreads();
        }
        if (i < end) {
            int e = base + s[t] - v;  // exclusive prefix
            off[i] = e;
            cursor[i] = e;
        }
        int roundsum = s[255];
        __syncthreads();
        base += roundsum;
    }
}

__global__ void scatter_kernel(const int* __restrict__ src,
                               const int* __restrict__ dst, int E,
                               int* __restrict__ cursor,
                               int* __restrict__ csr_src) {
    int i = blockIdx.x * blockDim.x + threadIdx.x;
    if (i < E) {
        int p = atomicAdd(&cursor[dst[i]], 1);
        csr_src[p] = src[i];
    }
}

// ---------------------------------------------------------------------------
// GEMM: H = X[N,128] @ W[128,128], fp32 vector ALU.
// 128 threads/block; each thread computes a 4x4 tile; block = 16 rows.
// ---------------------------------------------------------------------------
__global__ __launch_bounds__(128) void gemm128_kernel(
    const float* __restrict__ X, const float* __restrict__ W,
    float* __restrict__ Hout, int N) {
    __shared__ float sX[16 * 132];
    int t = threadIdx.x;
    int tx = t & 31;
    int ty = t >> 5;
    int row0 = blockIdx.x * 16;

    for (int i = t; i < 512; i += 128) {
        int r = i >> 5;
        int kq = i & 31;
        int row = row0 + r;
        float4 v = make_float4(0.f, 0.f, 0.f, 0.f);
        if (row < N) v = ((const float4*)X)[(size_t)row * 32 + kq];
        *(float4*)&sX[r * 132 + kq * 4] = v;
    }
    __syncthreads();

    float acc[4][4] = {};
    const float4* W4 = (const float4*)W;
#pragma unroll 4
    for (int k = 0; k < 128; ++k) {
        float4 b = W4[k * 32 + tx];
#pragma unroll
        for (int i = 0; i < 4; ++i) {
            float a = sX[(ty * 4 + i) * 132 + k];
            acc[i][0] += a * b.x;
            acc[i][1] += a * b.y;
            acc[i][2] += a * b.z;
            acc[i][3] += a * b.w;
        }
    }
#pragma unroll
    for (int i = 0; i < 4; ++i) {
        int row = row0 + ty * 4 + i;
        if (row < N) {
            float4 o = make_float4(acc[i][0], acc[i][1], acc[i][2], acc[i][3]);
            ((float4*)Hout)[(size_t)row * 32 + tx] = o;
        }
    }
}

// ---------------------------------------------------------------------------
// alpha_s[n,h] = sum_c h[n,h,c]*a_src[h,c] (same for alpha_d).
// One wave per node, 2 nodes per 128-thread block; shuffle reductions.
// ---------------------------------------------------------------------------
template <int C>
__global__ __launch_bounds__(128) void alpha_kernel(
    const float* __restrict__ h, const float* __restrict__ asrc,
    const float* __restrict__ adst, float* __restrict__ alpha_s,
    float* __restrict__ alpha_d, int N) {
    constexpr int H = 128 / C;
    constexpr int GL = C / 2;  // lanes per head (float2 per lane)
    int w = threadIdx.x >> 6;
    int lane = threadIdx.x & 63;
    int n = blockIdx.x * 2 + w;
    if (n >= N) return;
    float2 hv = ((const float2*)h)[(size_t)n * 64 + lane];
    float2 a1 = ((const float2*)asrc)[lane];
    float2 a2 = ((const float2*)adst)[lane];
    float p1 = hv.x * a1.x + hv.y * a1.y;
    float p2 = hv.x * a2.x + hv.y * a2.y;
#pragma unroll
    for (int o = GL / 2; o > 0; o >>= 1) {
        p1 += __shfl_xor(p1, o);
        p2 += __shfl_xor(p2, o);
    }
    if ((lane & (GL - 1)) == 0) {
        int hh = lane / GL;
        alpha_s[(size_t)n * H + hh] = p1;
        alpha_d[(size_t)n * H + hh] = p2;
    }
}

// ---------------------------------------------------------------------------
// Per-dst-node segment softmax + weighted aggregation.
// One WAVE per node (2 nodes / 128-thread block). Edge idx 0 = self-loop.
// Wave-lockstep LDS staging (no __syncthreads: per-node trip counts differ,
// and within-wave LDS ordering is program-order via lgkmcnt).
// ---------------------------------------------------------------------------
template <int H, int C>
__global__ __launch_bounds__(128) void gather_kernel(
    const float* __restrict__ h, const float* __restrict__ as_,
    const float* __restrict__ ad_, const int* __restrict__ off,
    const int* __restrict__ csr_src, const float* __restrict__ bias,
    float* __restrict__ out, int N) {
    __shared__ int s_src[2][64];
    __shared__ float s_w[2][64 * H];
    int w = threadIdx.x >> 6;
    int lane = threadIdx.x & 63;
    int n = blockIdx.x * 2 + w;
    if (n >= N) return;

    int beg = off[n];
    int total = off[n + 1] - beg + 1;  // + self loop

    float adv[H];
#pragma unroll
    for (int hh = 0; hh < H; ++hh) adv[hh] = ad_[(size_t)n * H + hh];

    // Pass 1a: per-head max (wave shuffle reduce)
    float m[H];
#pragma unroll
    for (int hh = 0; hh < H; ++hh) m[hh] = -3.4e38f;
    for (int idx = lane; idx < total; idx += 64) {
        int src = (idx == 0) ? n : csr_src[beg + idx - 1];
#pragma unroll
        for (int hh = 0; hh < H; ++hh) {
            float s = as_[(size_t)src * H + hh] + adv[hh];
            s = (s > 0.f) ? s : NEG_SLOPE * s;
            m[hh] = fmaxf(m[hh], s);
        }
    }
#pragma unroll
    for (int o = 32; o > 0; o >>= 1) {
#pragma unroll
        for (int hh = 0; hh < H; ++hh) m[hh] = fmaxf(m[hh], __shfl_xor(m[hh], o));
    }

    // Pass 1b: per-head sum of exp
    float dsum[H];
#pragma unroll
    for (int hh = 0; hh < H; ++hh) dsum[hh] = 0.f;
    for (int idx = lane; idx < total; idx += 64) {
        int src = (idx == 0) ? n : csr_src[beg + idx - 1];
#pragma unroll
        for (int hh = 0; hh < H; ++hh) {
            float s = as_[(size_t)src * H + hh] + adv[hh];
            s = (s > 0.f) ? s : NEG_SLOPE * s;
            dsum[hh] += __expf(s - m[hh]);
        }
    }
#pragma unroll
    for (int o = 32; o > 0; o >>= 1) {
#pragma unroll
        for (int hh = 0; hh < H; ++hh) dsum[hh] += __shfl_xor(dsum[hh], o);
    }
    float inv[H];
#pragma unroll
    for (int hh = 0; hh < H; ++hh) inv[hh] = 1.f / dsum[hh];

    // Pass 2: weighted accumulation; lane owns channels 2*lane, 2*lane+1.
    const int head_t = (2 * lane) / C;
    float2 acc = make_float2(0.f, 0.f);
    for (int base = 0; base < total; base += 64) {
        int cnt2 = min(64, total - base);
        if (lane < cnt2) {
            int idx = base + lane;
            int src = (idx == 0) ? n : csr_src[beg + idx - 1];
            s_src[w][lane] = src;
#pragma unroll
            for (int hh = 0; hh < H; ++hh) {
                float s = as_[(size_t)src * H + hh] + adv[hh];
                s = (s > 0.f) ? s : NEG_SLOPE * s;
                s_w[w][lane * H + hh] = __expf(s - m[hh]) * inv[hh];
            }
        }
        __builtin_amdgcn_wave_barrier();
        for (int j = 0; j < cnt2; ++j) {
            int src = s_src[w][j];
            float wt = s_w[w][j * H + head_t];
            float2 hv = ((const float2*)h)[(size_t)src * 64 + lane];
            acc.x += wt * hv.x;
            acc.y += wt * hv.y;
        }
        __builtin_amdgcn_wave_barrier();
    }
    float2 bv = ((const float2*)bias)[lane];
    float2 o2;
    o2.x = fmaxf(acc.x + bv.x, 0.f);
    o2.y = fmaxf(acc.y + bv.y, 0.f);
    ((float2*)out)[(size_t)n * 64 + lane] = o2;
}

// ---------------------------------------------------------------------------
extern "C" void kernel_launch(void* const* d_in, const int* in_sizes, int n_in,
                              void* d_out, int out_size, void* d_ws,
                              size_t ws_size, hipStream_t stream) {
    const float* x   = (const float*)d_in[0];
    const void*  ei  = d_in[1];
    const float* W0  = (const float*)d_in[2];
    const float* as0 = (const float*)d_in[3];
    const float* ad0 = (const float*)d_in[4];
    const float* b0  = (const float*)d_in[5];
    const float* W1  = (const float*)d_in[6];
    const float* as1 = (const float*)d_in[7];
    const float* ad1 = (const float*)d_in[8];
    const float* b1  = (const float*)d_in[9];
    const float* W2  = (const float*)d_in[10];
    const float* as2 = (const float*)d_in[11];
    const float* ad2 = (const float*)d_in[12];
    const float* b2  = (const float*)d_in[13];

    int N = in_sizes[0] / 128;
    int E = in_sizes[1] / 2;
    float* out = (float*)d_out;

    // workspace layout
    float* h       = (float*)d_ws;                       // N*128
    float* alpha_s = h + (size_t)N * 128;                // N*4 (max H)
    float* alpha_d = alpha_s + (size_t)N * 4;            // N*4
    int*   cnt     = (int*)(alpha_d + (size_t)N * 4);    // N
    int*   off     = cnt + N;                            // N+1
    int*   cursor  = off + N + 1;                        // N
    int*   partial = cursor + N;                         // SCAN_NB
    int*   src32   = partial + SCAN_NB;                  // E
    int*   dst32   = src32 + E;                          // E
    int*   csr     = dst32 + E;                          // E

    int eb = (E + 255) / 256;
    int nb = (N + 255) / 256;

    zero_kernel<<<nb, 256, 0, stream>>>(cnt, N);
    detect_convert_count_kernel<<<eb, 256, 0, stream>>>(ei, E, src32, dst32, cnt);
    scan1_kernel<<<SCAN_NB, 256, 0, stream>>>(cnt, partial, N);
    scan2_kernel<<<1, 256, 0, stream>>>(partial, off, N);
    scan3_kernel<<<SCAN_NB, 256, 0, stream>>>(cnt, partial, off, cursor, N);
    scatter_kernel<<<eb, 256, 0, stream>>>(src32, dst32, E, cursor, csr);

    int gb = (N + 15) / 16;
    int wb = (N + 1) / 2;  // 2 nodes (waves) per block

    // layer 0: H=4, C=32
    gemm128_kernel<<<gb, 128, 0, stream>>>(x, W0, h, N);
    alpha_kernel<32><<<wb, 128, 0, stream>>>(h, as0, ad0, alpha_s, alpha_d, N);
    gather_kernel<4, 32><<<wb, 128, 0, stream>>>(h, alpha_s, alpha_d, off, csr, b0, out, N);

    // layer 1: H=4, C=32
    gemm128_kernel<<<gb, 128, 0, stream>>>(out, W1, h, N);
    alpha_kernel<32><<<wb, 128, 0, stream>>>(h, as1, ad1, alpha_s, alpha_d, N);
    gather_kernel<4, 32><<<wb, 128, 0, stream>>>(h, alpha_s, alpha_d, off, csr, b1, out, N);

    // layer 2: H=1, C=128
    gemm128_kernel<<<gb, 128, 0, stream>>>(out, W2, h, N);
    alpha_kernel<128><<<wb, 128, 0, stream>>>(h, as2, ad2, alpha_s, alpha_d, N);
    gather_kernel<1, 128><<<wb, 128, 0, stream>>>(h, alpha_s, alpha_d, off, csr, b2, out, N);
}